// Round 17
// baseline (121.018 us; speedup 1.0000x reference)
//
#include <hip/hip_runtime.h>
#include <stdint.h>

#define VOCAB 21128
#define NUMC  53
#define EMB   128
#define SEQ   512
#define BATCH 512

typedef __bf16 bf16x8 __attribute__((ext_vector_type(8)));
typedef float f32x4 __attribute__((ext_vector_type(4)));

__device__ __forceinline__ unsigned int f2bf1(float f) {
    union { float f; unsigned int u; } v; v.f = f;
    return (v.u + 0x7FFFu + ((v.u >> 16) & 1u)) >> 16;
}
__device__ __forceinline__ unsigned int pack2(float a, float b) {
    return f2bf1(a) | (f2bf1(b) << 16);
}
__device__ __forceinline__ float b2f(unsigned short u) {
    union { float f; unsigned int i; } v; v.i = ((unsigned int)u) << 16; return v.f;
}

// Vocabulary-factored conv table (algebra verified r13/r15, absmax 9.77e-4):
//   P[id][tap*128+f] = sum_e emb[id,e]*w[f,e,tap],  bf16, VOCAB x 384 (16.2 MB)
// r16 consolidation: prep_w is GONE — each lane builds its two B fragments
// per K-step in-register from cw with the byte-identical formula prep_w used:
//   fragment (s, g=wn*2+nt), lane (quad,lc), elem j:
//   kk = s*32 + quad*8 + j; tap = kk>>7; e = kk&127; f = g*16+lc;
//   val = f2bf1(cw[f*384 + e*3 + tap])
// Within a j-octet (K0 = s*32+quad*8, K0 % 8 == 0) tap is constant and e is
// contiguous (octets never straddle a 128 boundary), so the 8 loads are
// base + j*12 B, all L2/L3-hot (cw = 196 KB, read by every block).
// A staged from fp32 emb into XOR-swizzled LDS (slot (r, c^(r&15)) holds
// chunk c). Accumulator split per tap (s>>2). C store = session-verified
// mapping (row=quad*4+reg, col=lc). emb row 0 = 0 -> P row 0 = 0 = padding.
__launch_bounds__(256)
__global__ void pcnn_vgemm(const float* __restrict__ emb,
                           const float* __restrict__ cw,
                           unsigned short* __restrict__ P) {
    __shared__ __align__(16) unsigned short As[64 * 128];  // 16 KB, swizzled

    const int tid  = threadIdx.x;
    const int lane = tid & 63;
    const int wn   = tid >> 6;
    const int quad = lane >> 4;
    const int lc   = lane & 15;
    const int row0 = blockIdx.x * 64;

    // Stage A: 64 rows x 16 chunks (8 bf16 = 16 B) = 1024 tasks, 4 passes.
#pragma unroll
    for (int i = 0; i < 4; ++i) {
        int task = tid + 256 * i;
        int r = task >> 4, c = task & 15;
        int gr = row0 + r;
        uint4 o = {0u, 0u, 0u, 0u};
        if (gr < VOCAB) {
            const float4* src = (const float4*)(emb + (size_t)gr * EMB + c * 8);
            float4 a = src[0], b = src[1];
            o.x = pack2(a.x, a.y); o.y = pack2(a.z, a.w);
            o.z = pack2(b.x, b.y); o.w = pack2(b.z, b.w);
        }
        *(uint4*)((char*)As + (r * 16 + (c ^ (r & 15))) * 16) = o;
    }
    __syncthreads();

    f32x4 acc[3][4][2];
#pragma unroll
    for (int t = 0; t < 3; ++t)
#pragma unroll
        for (int mt = 0; mt < 4; ++mt)
#pragma unroll
            for (int nt = 0; nt < 2; ++nt)
                acc[t][mt][nt] = (f32x4){0.f, 0.f, 0.f, 0.f};

    union U8 { bf16x8 v; unsigned short u[8]; };

#pragma unroll
    for (int s = 0; s < 12; ++s) {
        const int tap = s >> 2;                      // compile-time per unrolled s
        const int q   = (s & 3) * 4 + quad;          // e-octet within the 128-e row

        // In-register B fragments (formula identical to the verified prep_w).
        const int K0  = s * 32 + quad * 8;
        const int ft  = K0 >> 7;                     // tap of this octet
        const int e0  = K0 & 127;                    // first e of this octet
        bf16x8 bfr[2];
#pragma unroll
        for (int nt = 0; nt < 2; ++nt) {
            const int f = (wn * 2 + nt) * 16 + lc;
            const float* wp = cw + (size_t)f * 384 + e0 * 3 + ft;
            U8 bb;
#pragma unroll
            for (int j = 0; j < 8; ++j)
                bb.u[j] = (unsigned short)f2bf1(wp[j * 3]);
            bfr[nt] = bb.v;
        }

#pragma unroll
        for (int mt = 0; mt < 4; ++mt) {
            int r = mt * 16 + lc;
            bf16x8 a = *(const bf16x8*)(As + r * 128 + (q ^ (r & 15)) * 8);
            acc[tap][mt][0] = __builtin_amdgcn_mfma_f32_16x16x32_bf16(a, bfr[0], acc[tap][mt][0], 0, 0, 0);
            acc[tap][mt][1] = __builtin_amdgcn_mfma_f32_16x16x32_bf16(a, bfr[1], acc[tap][mt][1], 0, 0, 0);
        }
    }

    // Store P[gr][tap*128 + f] bf16 (verified C mapping row=quad*4+reg, col=lc).
#pragma unroll
    for (int tap = 0; tap < 3; ++tap)
#pragma unroll
        for (int mt = 0; mt < 4; ++mt) {
            int grb = row0 + mt * 16 + quad * 4;
#pragma unroll
            for (int nt = 0; nt < 2; ++nt) {
                int col = tap * 128 + (wn * 2 + nt) * 16 + lc;
#pragma unroll
                for (int reg = 0; reg < 4; ++reg) {
                    int gr = grb + reg;
                    if (gr < VOCAB)
                        P[(size_t)gr * 384 + col] = (unsigned short)f2bf1(acc[tap][mt][nt][reg]);
                }
            }
        }
}

// Fused gather + pool + FC (verbatim r15-verified thin-request version):
// 512 blocks, one per batch row; 1024 threads = 16 waves (2 blocks/CU, full
// 32-wave residency). f = tid&127, half = tid>>7. Per position: 3 bf16
// lookups into L3-resident P (wave reads 64 consecutive bf16 = one 128 B line
// per tap), fp32 sum, masked 3-segment max in registers; then in-block
// 8-plane reduce, bias+ReLU, FC 384->53. r16 proved this is byte-BW-bound
// (fat requests neutral), running at ~76-80% of streaming BW — the
// pattern-specific ceiling for a random gather.
__launch_bounds__(1024)
__global__ void pcnn_gather_fc(const int* __restrict__ cid, const int* __restrict__ p1,
                               const int* __restrict__ p2,
                               const unsigned short* __restrict__ P,
                               const float* __restrict__ cb,
                               const float* __restrict__ fcw,
                               const float* __restrict__ fcb,
                               float* __restrict__ out) {
    __shared__ int idsB[514];             // idsB[i] = P-row byte offset at pos i-1
    __shared__ float pstage[8][3][128];   // 12 KB
    __shared__ float pooled[384];
    __shared__ float fcred[NUMC][4];

    const int b   = blockIdx.x;
    const int tid = threadIdx.x;

    const int* crow = cid + (size_t)b * SEQ;
    for (int i = tid; i < 514; i += 1024) {
        int p = i - 1;
        unsigned int id = (p >= 0 && p < SEQ) ? (unsigned int)crow[p] : 0u;
        idsB[i] = (int)(id * 768u);       // 384 cols x 2 B
    }

    int e1 = min(p1[b], p2[b]);
    int e2 = max(p1[b], p2[b]);
    if (e1 == e2) e2 = min(e1 + 1, SEQ);
    const int e1m = max(e1, 1);

    __syncthreads();

    const int f    = tid & 127;
    const int half = tid >> 7;            // 0..7
    const char* Pb = (const char*)P;
    const int o0 = f * 2;                 // tap 0: id at l-1
    const int o1 = 256 + f * 2;           // tap 1: id at l
    const int o2 = 512 + f * 2;           // tap 2: id at l+1

    float smax0 = -1e30f, smax1 = -1e30f, smax2 = -1e30f;

#pragma unroll 4
    for (int pass = 0; pass < 64; ++pass) {
        int p = pass * 8 + half;          // position 0..511
        float v = b2f(*(const unsigned short*)(Pb + idsB[p]     + o0))
                + b2f(*(const unsigned short*)(Pb + idsB[p + 1] + o1))
                + b2f(*(const unsigned short*)(Pb + idsB[p + 2] + o2));
        smax0 = fmaxf(smax0, v + ((p < e1m)           ? 0.f : -2e30f));
        smax1 = fmaxf(smax1, v + ((p >= e1 && p < e2) ? 0.f : -2e30f));
        smax2 = fmaxf(smax2, v + ((p >= e2)           ? 0.f : -2e30f));
    }

    pstage[half][0][f] = smax0;
    pstage[half][1][f] = smax1;
    pstage[half][2][f] = smax2;
    __syncthreads();

    // Reduce 8 half-planes -> pooled[384] with bias+ReLU.
    if (tid < 384) {
        int s3 = tid >> 7, ff = tid & 127;
        float m = pstage[0][s3][ff];
#pragma unroll
        for (int h = 1; h < 8; ++h) m = fmaxf(m, pstage[h][s3][ff]);
        pooled[tid] = fmaxf(m + cb[ff], 0.f);
    }
    __syncthreads();

    // FC 384 -> 53 (verbatim verified combine; summation order preserved).
    if (tid < 212) {
        int c = tid >> 2, q = tid & 3;
        const float* wrow = fcw + (size_t)c * 384 + q * 96;
        const float* pp   = pooled + q * 96;
        float sum = 0.f;
#pragma unroll 8
        for (int i = 0; i < 96; ++i) sum += wrow[i] * pp[i];
        fcred[c][q] = sum;
    }
    __syncthreads();
    if (tid < NUMC)
        out[(size_t)b * NUMC + tid] =
            fcred[tid][0] + fcred[tid][1] + fcred[tid][2] + fcred[tid][3] + fcb[tid];
}

extern "C" void kernel_launch(void* const* d_in, const int* in_sizes, int n_in,
                              void* d_out, int out_size, void* d_ws, size_t ws_size,
                              hipStream_t stream) {
    const int*   cid = (const int*)d_in[0];
    const int*   p1  = (const int*)d_in[1];
    const int*   p2  = (const int*)d_in[2];
    const float* emb = (const float*)d_in[3];
    const float* cw  = (const float*)d_in[4];
    const float* cb  = (const float*)d_in[5];
    const float* fcw = (const float*)d_in[6];
    const float* fcb = (const float*)d_in[7];
    float* out = (float*)d_out;

    // ws: P bf16 [VOCAB*384] (16,226,304 B)
    unsigned short* P = (unsigned short*)d_ws;

    const int gemm_blocks = (VOCAB + 63) / 64;  // 331
    pcnn_vgemm<<<gemm_blocks, 256, 0, stream>>>(emb, cw, P);
    pcnn_gather_fc<<<BATCH, 1024, 0, stream>>>(cid, p1, p2, P, cb, fcw, fcb, out);
}

// Round 18
// 114.560 us; speedup vs baseline: 1.0564x; 1.0564x over previous
//
#include <hip/hip_runtime.h>
#include <stdint.h>

#define VOCAB 21128
#define NUMC  53
#define EMB   128
#define SEQ   512
#define BATCH 512

typedef __bf16 bf16x8 __attribute__((ext_vector_type(8)));
typedef float f32x4 __attribute__((ext_vector_type(4)));
typedef __attribute__((address_space(3))) void lds_void;
typedef const __attribute__((address_space(1))) void glob_void;

__device__ __forceinline__ unsigned int f2bf1(float f) {
    union { float f; unsigned int u; } v; v.f = f;
    return (v.u + 0x7FFFu + ((v.u >> 16) & 1u)) >> 16;
}
__device__ __forceinline__ unsigned int pack2(float a, float b) {
    return f2bf1(a) | (f2bf1(b) << 16);
}

// Prep: emb_table fp32 -> bf16 Tb[VOCAB][128] (8 elem/thread, vectorized);
// conv_w -> Wp bf16 in per-lane B-fragment order (16x16x32, verified r1-r10):
// Wp[s 0..11][g 0..7][lane 0..63][j 0..7] = w[f=g*16+(lane&15)][e=kk&127][tap=kk>>7],
// kk = s*32 + (lane>>4)*8 + j
__global__ void prep_kernel(const float* __restrict__ emb, const float* __restrict__ cw,
                            unsigned short* __restrict__ Tb, unsigned short* __restrict__ Wp) {
    int idx = blockIdx.x * blockDim.x + threadIdx.x;
    const int n8 = VOCAB * EMB / 8;  // 338048
    if (idx < n8) {
        const float4* src = (const float4*)emb + (size_t)idx * 2;
        float4 a = src[0], b = src[1];
        uint4 o;
        o.x = pack2(a.x, a.y);
        o.y = pack2(a.z, a.w);
        o.z = pack2(b.x, b.y);
        o.w = pack2(b.z, b.w);
        *(uint4*)(Tb + (size_t)idx * 8) = o;
    }
    if (idx < 12 * 8 * 64 * 8) {
        int j = idx & 7, l = (idx >> 3) & 63, g = (idx >> 9) & 7, s = idx >> 12;
        int kk = s * 32 + (l >> 4) * 8 + j;
        int f = g * 16 + (l & 15);
        int tap = kk >> 7, e = kk & 127;
        Wp[idx] = (unsigned short)f2bf1(cw[(f * EMB + e) * 3 + tap]);
    }
}

// 2048 blocks: block (b, tq) = batch row b, positions [tq*128, tq*128+128).
// 512 threads = 8 waves; wave w: wm=w&1 (64-pos half), wn=w>>1 (32-filter group).
// SESSION-FINAL anchor (113.7 µs, r10 bench). Ledger (r0-r17): the tile's
// ~42 µs is a scattered-line byte-bandwidth wall (~4.8-5 TB/s, 76-80% of the
// streaming ceiling — the random-gather maximum), invariant to LDS volume,
// B-traffic, occupancy, wave shape, request count/width, L2 warmth, and
// pipelining; an algebraically independent vocabulary-factored algorithm
// (P-table, r13-r17) hits the same wall at 115.8-121. Fusion (r2/r3),
// fence-based cross-block reduction (r9: 362 µs), and dispatch consolidation
// (r17: scalar B build +10 µs > gap -5.5 µs) all regressed.
//
// Pass A line-warming (neutral in r8, part of the measured binary): opens each
// of the block's 260 Tb lines once via the normal VMEM path.
// Staging via global_load_lds (16 B DMA, per-lane gather addr, wave-uniform LDS
// dest = base + lane*16): zero VGPR round-trip, zero pack VALU. LDS rows are
// UNPADDED 256 B (DMA requires contiguity); bank conflicts broken by an XOR
// swizzle within each row: LDS slot (r,c) holds global chunk c^(r&15).
// B fragments loaded IN-LOOP from L2-hot Wp (r11: preloading costs occupancy).
__launch_bounds__(512)
__global__ void pcnn_tile(const int* __restrict__ cid, const int* __restrict__ p1,
                          const int* __restrict__ p2,
                          const unsigned short* __restrict__ Tb,
                          const unsigned short* __restrict__ Wp,
                          float* __restrict__ Pd) {
    __shared__ __align__(16) unsigned short xs[130 * 128];  // 33,280 B, unpadded
    __shared__ float pstage[2][3][128];                     // 3,072 B

    const int bx   = blockIdx.x;
    const int b    = bx >> 2;
    const int tq   = bx & 3;
    const int tid  = threadIdx.x;
    const int lane = tid & 63;
    const int w    = tid >> 6;
    const int wm   = w & 1;
    const int wn   = w >> 1;
    const int quad = lane >> 4;
    const int lc   = lane & 15;

    const int* crow = cid + (size_t)b * SEQ;
    const char* TbB = (const char*)Tb;
    char* xsB = (char*)xs;

    // ---- Pass A: open each of the block's 260 Tb lines once (coalesced dword
    // per line, all lines distinct). asm sink keeps the loads live (rule #17).
    if (tid < 260) {
        int r = tid >> 1, h = tid & 1;
        int p = tq * 128 + r - 1;
        unsigned int id = (p >= 0 && p < SEQ) ? (unsigned int)crow[p] : 0u;
        unsigned int warm = *(const unsigned int*)(TbB + (size_t)id * 256u + h * 128);
        asm volatile("" :: "v"(warm));
    }
    __syncthreads();  // vmcnt(0)+barrier: warm fills complete before DMA issue

    // ---- Stage: 130 rows x 16 chunks = 2080 tasks; row r <-> pos tq*128 + r - 1.
    // OOB -> id 0 (Tb row 0 all zeros). Lane loads global chunk (c ^ (r&15)) of
    // its row; DMA places it at LDS slot task*16 (= base + lane*16 within a wave).
#pragma unroll
    for (int i = 0; i < 5; ++i) {
        int task = tid + 512 * i;
        if (task < 2080) {
            int r = task >> 4, c = task & 15;
            int p = tq * 128 + r - 1;
            unsigned int id = (p >= 0 && p < SEQ) ? (unsigned int)crow[p] : 0u;
            int cs = c ^ (r & 15);
            __builtin_amdgcn_global_load_lds(
                (glob_void*)(TbB + (size_t)id * 256u + cs * 16),
                (lds_void*)(xsB + task * 16), 16, 0, 0);
        }
    }

    int e1 = min(p1[b], p2[b]);
    int e2 = max(p1[b], p2[b]);
    if (e1 == e2) e2 = min(e1 + 1, SEQ);
    const int e1m = max(e1, 1);

    __syncthreads();  // full vmcnt drain + barrier

    // ---- Conv via MFMA 16x16x32 bf16: M=128 (wm half x 4 mt), N=32/wave (2 nt), K=384
    f32x4 acc[4][2];
#pragma unroll
    for (int mt = 0; mt < 4; ++mt)
#pragma unroll
        for (int nt = 0; nt < 2; ++nt)
            acc[mt][nt] = (f32x4){0.f, 0.f, 0.f, 0.f};

#pragma unroll
    for (int s = 0; s < 12; ++s) {
        const int tap = s >> 2;
        const int q   = (s & 3) * 4 + quad;             // global 16 B chunk wanted
        const int cs  = q ^ ((lc + tap) & 15);          // swizzled LDS chunk (= q^(r&15))
        bf16x8 b0 = *(const bf16x8*)(Wp + (size_t)((s * 8 + wn * 2) * 64 + lane) * 8);
        bf16x8 b1 = *(const bf16x8*)(Wp + (size_t)((s * 8 + wn * 2 + 1) * 64 + lane) * 8);
        bf16x8 af[4];
#pragma unroll
        for (int mt = 0; mt < 4; ++mt) {
            int r = wm * 64 + mt * 16 + lc + tap;
            af[mt] = *(const bf16x8*)(xs + r * 128 + cs * 8);
        }
#pragma unroll
        for (int mt = 0; mt < 4; ++mt) {
            acc[mt][0] = __builtin_amdgcn_mfma_f32_16x16x32_bf16(af[mt], b0, acc[mt][0], 0, 0, 0);
            acc[mt][1] = __builtin_amdgcn_mfma_f32_16x16x32_bf16(af[mt], b1, acc[mt][1], 0, 0, 0);
        }
    }

    // ---- Piecewise max over this tile's 128 positions (raw conv; bias+relu in combine)
    float smax[3][2];
#pragma unroll
    for (int s3 = 0; s3 < 3; ++s3) { smax[s3][0] = -1e30f; smax[s3][1] = -1e30f; }

#pragma unroll
    for (int mt = 0; mt < 4; ++mt)
#pragma unroll
        for (int reg = 0; reg < 4; ++reg) {
            int p = tq * 128 + wm * 64 + mt * 16 + quad * 4 + reg;
            float a0 = (p < e1m) ? 0.f : -2e30f;
            float a1 = (p >= e1 && p < e2) ? 0.f : -2e30f;
            float a2 = (p >= e2) ? 0.f : -2e30f;
#pragma unroll
            for (int nt = 0; nt < 2; ++nt) {
                float v = acc[mt][nt][reg];
                smax[0][nt] = fmaxf(smax[0][nt], v + a0);
                smax[1][nt] = fmaxf(smax[1][nt], v + a1);
                smax[2][nt] = fmaxf(smax[2][nt], v + a2);
            }
        }

    // Quad reduction in-register (butterfly over lanes ^16, ^32)
#pragma unroll
    for (int s3 = 0; s3 < 3; ++s3)
#pragma unroll
        for (int nt = 0; nt < 2; ++nt) {
            float v = smax[s3][nt];
            v = fmaxf(v, __shfl_xor(v, 16));
            v = fmaxf(v, __shfl_xor(v, 32));
            smax[s3][nt] = v;
        }
    if (lane < 16) {
#pragma unroll
        for (int s3 = 0; s3 < 3; ++s3)
#pragma unroll
            for (int nt = 0; nt < 2; ++nt)
                pstage[wm][s3][(wn * 2 + nt) * 16 + lc] = smax[s3][nt];
    }
    __syncthreads();

    if (tid < 384) {
        int s3 = tid >> 7, f = tid & 127;
        Pd[((size_t)b * 4 + tq) * 384 + tid] = fmaxf(pstage[0][s3][f], pstage[1][s3][f]);
    }
}

// Combine: max over the 4 tile-partials, bias+ReLU, FC 384->53. One block per row.
__launch_bounds__(256)
__global__ void pcnn_combine(const float* __restrict__ Pd, const float* __restrict__ cb,
                             const float* __restrict__ fcw, const float* __restrict__ fcb,
                             float* __restrict__ out) {
    __shared__ float pooled[384];
    __shared__ float fcred[NUMC][4];
    const int b = blockIdx.x;
    const int tid = threadIdx.x;

    for (int j = tid; j < 384; j += 256) {
        const float* pp = Pd + (size_t)b * 4 * 384 + j;
        float m = fmaxf(fmaxf(pp[0], pp[384]), fmaxf(pp[768], pp[1152]));
        pooled[j] = fmaxf(m + cb[j & 127], 0.f);
    }
    __syncthreads();

    if (tid < 212) {
        int c = tid >> 2, q = tid & 3;
        const float* wrow = fcw + (size_t)c * 384 + q * 96;
        const float* pp   = pooled + q * 96;
        float sum = 0.f;
#pragma unroll 8
        for (int i = 0; i < 96; ++i) sum += wrow[i] * pp[i];
        fcred[c][q] = sum;
    }
    __syncthreads();
    if (tid < NUMC)
        out[(size_t)b * NUMC + tid] =
            fcred[tid][0] + fcred[tid][1] + fcred[tid][2] + fcred[tid][3] + fcb[tid];
}

extern "C" void kernel_launch(void* const* d_in, const int* in_sizes, int n_in,
                              void* d_out, int out_size, void* d_ws, size_t ws_size,
                              hipStream_t stream) {
    const int*   cid = (const int*)d_in[0];
    const int*   p1  = (const int*)d_in[1];
    const int*   p2  = (const int*)d_in[2];
    const float* emb = (const float*)d_in[3];
    const float* cw  = (const float*)d_in[4];
    const float* cb  = (const float*)d_in[5];
    const float* fcw = (const float*)d_in[6];
    const float* fcb = (const float*)d_in[7];
    float* out = (float*)d_out;

    // ws: Tb bf16 [VOCAB*128] (5,408,768 B) | Wp bf16 [49152] (98,304 B)
    //   | Pd fp32 [512*4*384] (3,145,728 B)
    unsigned short* Tb = (unsigned short*)d_ws;
    unsigned short* Wp = (unsigned short*)((char*)d_ws + (size_t)VOCAB * EMB * 2);
    float*          Pd = (float*)((char*)d_ws + (size_t)VOCAB * EMB * 2 + 98304);

    const int n8 = VOCAB * EMB / 8;
    const int prep_threads = 256;
    const int prep_blocks  = (n8 + prep_threads - 1) / prep_threads;
    prep_kernel<<<prep_blocks, prep_threads, 0, stream>>>(emb, cw, Tb, Wp);
    pcnn_tile<<<BATCH * 4, 512, 0, stream>>>(cid, p1, p2, Tb, Wp, Pd);
    pcnn_combine<<<BATCH, 256, 0, stream>>>(Pd, cb, fcw, fcb, out);
}